// Round 3
// baseline (176.629 us; speedup 1.0000x reference)
//
#include <hip/hip_runtime.h>
#include <math.h>

// RX gate on qubit 10 of a 22-qubit state, batch=4. Output = REAL PART only
// (fp32, 2^24 elems), verified (absmax 0.0156).
//   o0re = c*r0 + s*i1 ; o1re = c*r1 + s*i0   per batch lane.
//
// R2 counters (first clean bench this session): dispatch 41.5 us,
// FETCH=64 MiB (of 128 MiB logical reads -> half already L3-resident),
// WRITE=64 MiB, 3.23 TB/s (40%). Harness fill kernels hit 6.5 TB/s on the
// same chip -> we're at half of achievable, VALU 6%, occupancy fine.
//
// R3 change (single variable): drop nontemporal hint on LOADS only.
// Theory: inputs re+im (128 MiB) fit in the 256 MiB Infinity Cache across
// graph replays; our nt-load hint prevents allocation and throws away that
// residency. Keep nt on stores (output never re-read; don't evict inputs).
// Prediction: FETCH 64 MiB -> <=32 MiB, dispatch 41.5 -> ~28-34 us.

#define QC 2048
#define QB 4
#define JSTRIDE (QC * QB)   // 8192 floats between j=0 and j=1 slices
#define ITERS 4
#define NT     (1 << 21)    // total (a,c) pairs
#define NTHREADS (NT / ITERS)       // 524288
#define NBLOCKS  (NTHREADS / 256)   // 2048

typedef __attribute__((ext_vector_type(4))) float f32x4;

__global__ __launch_bounds__(256) void rx_gate_kernel(
    const float* __restrict__ theta,
    const float* __restrict__ re,
    const float* __restrict__ im,
    float* __restrict__ out,
    int out_n)
{
    const int t0 = blockIdx.x * blockDim.x + threadIdx.x;   // [0, 2^19)

    // theta is wave-uniform (same address) -> scalar load + 4 sincos, once
    float c[QB], s[QB];
    {
        const f32x4 th = *reinterpret_cast<const f32x4*>(theta);
        sincosf(0.5f * th.x, &s[0], &c[0]);
        sincosf(0.5f * th.y, &s[1], &c[1]);
        sincosf(0.5f * th.z, &s[2], &c[2]);
        sincosf(0.5f * th.w, &s[3], &c[3]);
    }

#pragma unroll
    for (int k = 0; k < ITERS; ++k) {
        const int t = t0 + k * NTHREADS;                      // consecutive lanes -> consecutive t
        const int idx0 = (((t >> 11) << 12) | (t & 2047)) * QB;  // j=0 base (16B aligned)
        const int idx1 = idx0 + JSTRIDE;                         // j=1

        // Plain (cache-allocating) loads: let re/im become L3-resident
        // across graph replays. (R2: nt loads -> FETCH 64 MiB; expect drop.)
        const f32x4 r0 = *reinterpret_cast<const f32x4*>(re + idx0);
        const f32x4 i0 = *reinterpret_cast<const f32x4*>(im + idx0);
        const f32x4 r1 = *reinterpret_cast<const f32x4*>(re + idx1);
        const f32x4 i1 = *reinterpret_cast<const f32x4*>(im + idx1);

        f32x4 o0, o1;
        o0.x = c[0] * r0.x + s[0] * i1.x;
        o0.y = c[1] * r0.y + s[1] * i1.y;
        o0.z = c[2] * r0.z + s[2] * i1.z;
        o0.w = c[3] * r0.w + s[3] * i1.w;
        o1.x = c[0] * r1.x + s[0] * i0.x;
        o1.y = c[1] * r1.y + s[1] * i0.y;
        o1.z = c[2] * r1.z + s[2] * i0.z;
        o1.w = c[3] * r1.w + s[3] * i0.w;

        if (idx0 + 3 < out_n)
            __builtin_nontemporal_store(o0, reinterpret_cast<f32x4*>(out + idx0));
        if (idx1 + 3 < out_n)
            __builtin_nontemporal_store(o1, reinterpret_cast<f32x4*>(out + idx1));
    }
}

extern "C" void kernel_launch(void* const* d_in, const int* in_sizes, int n_in,
                              void* d_out, int out_size, void* d_ws, size_t ws_size,
                              hipStream_t stream) {
    // setup_inputs order: theta[4], state_re[2^24], state_im[2^24], P[4] (fp32)
    const float* theta = (const float*)d_in[0];
    const float* re    = (const float*)d_in[1];
    const float* im    = (const float*)d_in[2];
    float* out = (float*)d_out;

    rx_gate_kernel<<<NBLOCKS, 256, 0, stream>>>(theta, re, im, out, out_size);
}

// Round 4
// 163.619 us; speedup vs baseline: 1.0795x; 1.0795x over previous
//
#include <hip/hip_runtime.h>
#include <math.h>

// RX gate on qubit 10 of a 22-qubit state, batch=4. Output = REAL PART only
// (fp32, 2^24 elems), verified (absmax 0.0156).
//   o0re = c*r0 + s*i1 ; o1re = c*r1 + s*i0   per batch lane.
//
// Session ledger:
//  R2 (nt loads+stores, ITERS=4): 41.5 us, FETCH=64 MiB WRITE=64 MiB,
//     3.23 TB/s HBM (40%), VALU 6%. Harness fill hits 6.5 TB/s same chip.
//  R3 (plain loads, single-variable): 61 us, FETCH UNCHANGED 64 MiB.
//     Lesson: input L3-residency is set by the harness (its 256 MiB fills
//     thrash L3), not our hint; nt-on-loads is worth 1.5x THROUGHPUT by
//     bypassing L2 allocation. KEEP nt loads.
//  R4 (this): ITERS 4 -> 1, grid 2048 -> 8192 blocks. Kill the per-wave
//     4x {load-burst -> vmcnt wait -> store} round-trip chain and the
//     16 MiB k-stride jumps; wave turnover replaces in-wave pipelining.
//     Predict: FETCH/WRITE unchanged; 41.5 -> ~30-35 us if wave-chain
//     serialization was real; null => fabric-capped at ~4.8 TB/s mixed.

#define QC 2048
#define QB 4
#define JSTRIDE (QC * QB)   // 8192 floats between j=0 and j=1 slices
#define NT     (1 << 21)    // total (a,c) pairs == total threads
#define NBLOCKS  (NT / 256) // 8192

typedef __attribute__((ext_vector_type(4))) float f32x4;

__global__ __launch_bounds__(256) void rx_gate_kernel(
    const float* __restrict__ theta,
    const float* __restrict__ re,
    const float* __restrict__ im,
    float* __restrict__ out,
    int out_n)
{
    const int t = blockIdx.x * blockDim.x + threadIdx.x;     // [0, 2^21)

    // theta is wave-uniform (same address) -> scalar load + 4 sincos, once
    float c[QB], s[QB];
    {
        const f32x4 th = *reinterpret_cast<const f32x4*>(theta);
        sincosf(0.5f * th.x, &s[0], &c[0]);
        sincosf(0.5f * th.y, &s[1], &c[1]);
        sincosf(0.5f * th.z, &s[2], &c[2]);
        sincosf(0.5f * th.w, &s[3], &c[3]);
    }

    const int idx0 = (((t >> 11) << 12) | (t & 2047)) * QB;  // j=0 base (16B aligned)
    const int idx1 = idx0 + JSTRIDE;                         // j=1

    const f32x4 r0 = __builtin_nontemporal_load(reinterpret_cast<const f32x4*>(re + idx0));
    const f32x4 i0 = __builtin_nontemporal_load(reinterpret_cast<const f32x4*>(im + idx0));
    const f32x4 r1 = __builtin_nontemporal_load(reinterpret_cast<const f32x4*>(re + idx1));
    const f32x4 i1 = __builtin_nontemporal_load(reinterpret_cast<const f32x4*>(im + idx1));

    f32x4 o0, o1;
    o0.x = c[0] * r0.x + s[0] * i1.x;
    o0.y = c[1] * r0.y + s[1] * i1.y;
    o0.z = c[2] * r0.z + s[2] * i1.z;
    o0.w = c[3] * r0.w + s[3] * i1.w;
    o1.x = c[0] * r1.x + s[0] * i0.x;
    o1.y = c[1] * r1.y + s[1] * i0.y;
    o1.z = c[2] * r1.z + s[2] * i0.z;
    o1.w = c[3] * r1.w + s[3] * i0.w;

    if (idx0 + 3 < out_n)
        __builtin_nontemporal_store(o0, reinterpret_cast<f32x4*>(out + idx0));
    if (idx1 + 3 < out_n)
        __builtin_nontemporal_store(o1, reinterpret_cast<f32x4*>(out + idx1));
}

extern "C" void kernel_launch(void* const* d_in, const int* in_sizes, int n_in,
                              void* d_out, int out_size, void* d_ws, size_t ws_size,
                              hipStream_t stream) {
    // setup_inputs order: theta[4], state_re[2^24], state_im[2^24], P[4] (fp32)
    const float* theta = (const float*)d_in[0];
    const float* re    = (const float*)d_in[1];
    const float* im    = (const float*)d_in[2];
    float* out = (float*)d_out;

    rx_gate_kernel<<<NBLOCKS, 256, 0, stream>>>(theta, re, im, out, out_size);
}